// Round 9
// baseline (192.804 us; speedup 1.0000x reference)
//
#include <hip/hip_runtime.h>

// Shape: (B=2, C=1, D=160, H=192, W=160) fp32. win=9/dim, win_size=9 (faithful bug).
#define B_ 2
#define D_ 160
#define H_ 192
#define W_ 160
#define W4_ (W_ / 4)                         // 40
#define HW_ (H_ * W_)                        // 30720
#define DHW_ (D_ * HW_)                      // 4,915,200
#define NV_ ((long long)B_ * D_ * H_ * W_)   // 9,830,400

#define ROWS 8
#define ZCH 10
#define NZC (D_ / ZCH)       // 16
#define PAD 4
#define LROW (W_ + 2 * PAD)  // 168

__global__ void k_zero(double* acc) { *acc = 0.0; }

// Accumulate (SGN=+1) or remove (SGN=-1) the 9-row y-window of the 5 product
// maps at z-slice zi into s[5], for this thread's 4 x-columns.
// 18 float4 global loads + 20 VALU/row. Rows are L1/L2-resident (block reuse).
template<int SGN>
__device__ __forceinline__ void ysum9(float4 s[5],
                                      const float* __restrict__ pI,
                                      const float* __restrict__ pJ,
                                      int zi, int y) {
    const float* rowI = pI + (size_t)zi * HW_;
    const float* rowJ = pJ + (size_t)zi * HW_;
#pragma unroll
    for (int dy = -4; dy <= 4; ++dy) {
        const int yy = y + dy;
        if ((unsigned)yy < (unsigned)H_) {
            const float4 a  = *(const float4*)(rowI + (size_t)yy * W_);
            const float4 bb = *(const float4*)(rowJ + (size_t)yy * W_);
            if (SGN > 0) {
                s[0].x += a.x;         s[0].y += a.y;         s[0].z += a.z;         s[0].w += a.w;
                s[1].x += bb.x;        s[1].y += bb.y;        s[1].z += bb.z;        s[1].w += bb.w;
                s[2].x += a.x * a.x;   s[2].y += a.y * a.y;   s[2].z += a.z * a.z;   s[2].w += a.w * a.w;
                s[3].x += bb.x * bb.x; s[3].y += bb.y * bb.y; s[3].z += bb.z * bb.z; s[3].w += bb.w * bb.w;
                s[4].x += a.x * bb.x;  s[4].y += a.y * bb.y;  s[4].z += a.z * bb.z;  s[4].w += a.w * bb.w;
            } else {
                s[0].x -= a.x;         s[0].y -= a.y;         s[0].z -= a.z;         s[0].w -= a.w;
                s[1].x -= bb.x;        s[1].y -= bb.y;        s[1].z -= bb.z;        s[1].w -= bb.w;
                s[2].x -= a.x * a.x;   s[2].y -= a.y * a.y;   s[2].z -= a.z * a.z;   s[2].w -= a.w * a.w;
                s[3].x -= bb.x * bb.x; s[3].y -= bb.y * bb.y; s[3].z -= bb.z * bb.z; s[3].w -= bb.w * bb.w;
                s[4].x -= a.x * bb.x;  s[4].y -= a.y * bb.y;  s[4].z -= a.z * bb.z;  s[4].w -= a.w * bb.w;
            }
        }
    }
}

// ---------------------------------------------------------------------------
// Fully fused: y-window (direct 9-row sums) + z-window (two-pointer running
// sums, trail recomputed from cache-resident inputs) + x-window (LDS, 3x
// float4 per channel) + cc + block reduction. No intermediate array.
// Block = 8 rows x 40 lanes (320 thr); thread owns 4 x-cols, marches z-chunk
// of 10. Grid = 16 z-chunks x 48 row-groups = 768 blocks.
// ---------------------------------------------------------------------------
__global__ __launch_bounds__(320) void kf_fused(const float* __restrict__ I,
                                                const float* __restrict__ J,
                                                double* __restrict__ acc) {
    __shared__ float sbuf[ROWS][5][LROW];    // 26.88 KB
    __shared__ float red[512];
    const int tid = threadIdx.x;             // 0..319
    const int r   = tid / W4_;               // 0..7
    const int l   = tid - r * W4_;           // 0..39
    const int x4  = l * 4;
    const int zc  = blockIdx.x % NZC;
    const int rp  = blockIdx.x / NZC;        // 0..47
    const int gy  = rp * ROWS + r;           // 0..383 (192%8==0: no b straddle)
    const int b   = gy / H_;
    const int y   = gy - b * H_;
    const int z0  = zc * ZCH;

    const float* pI = I + (size_t)b * DHW_ + x4;
    const float* pJ = J + (size_t)b * DHW_ + x4;

    {   // zero LDS once (pads must stay 0; interior overwritten every step)
        float* p = &sbuf[0][0][0];
        for (int i = tid; i < ROWS * 5 * LROW; i += ROWS * W4_) p[i] = 0.f;
    }

    float4 s[5];
#pragma unroll
    for (int c = 0; c < 5; ++c) s[c] = make_float4(0.f, 0.f, 0.f, 0.f);

    // prime z-window [z0-4, z0+3] (clipped; z0+3 <= 153 < D always)
    for (int j = 0; j < 8; ++j) {
        const int zi = z0 - 4 + j;
        if (zi >= 0) ysum9<+1>(s, pI, pJ, zi, y);
    }
    __syncthreads();                         // LDS zero visible

    float local = 0.f;
    for (int k = 0; k < ZCH; ++k) {
        const int zo = z0 + k;
        const int zi = zo + 4;               // lead (block-uniform branch)
        if (zi < D_) ysum9<+1>(s, pI, pJ, zi, y);
        const int zt = zo - 5;               // trail (rows are L2-hits)
        if (zt >= 0) ysum9<-1>(s, pI, pJ, zt, y);

#pragma unroll
        for (int c = 0; c < 5; ++c)
            *(float4*)&sbuf[r][c][PAD + x4] = s[c];
        __syncthreads();

        float4 S5[5];
#pragma unroll
        for (int c = 0; c < 5; ++c) {
            // window start (x4-4) sits at LDS index PAD+x4-4 = x4: aligned.
            const float4 a0 = *(const float4*)&sbuf[r][c][x4];
            const float4 a1 = *(const float4*)&sbuf[r][c][x4 + 4];
            const float4 a2 = *(const float4*)&sbuf[r][c][x4 + 8];
            const float o0 = a0.x + a0.y + a0.z + a0.w + a1.x + a1.y + a1.z + a1.w + a2.x;
            const float o1 = o0 - a0.x + a2.y;
            const float o2 = o1 - a0.y + a2.z;
            const float o3 = o2 - a0.z + a2.w;
            S5[c] = make_float4(o0, o1, o2, o3);
        }
        const float inv9 = 1.0f / 9.0f;
        {
            const float cr = S5[4].x - S5[1].x * S5[0].x * inv9;
            const float iv = S5[2].x - S5[0].x * S5[0].x * inv9;
            const float jv = S5[3].x - S5[1].x * S5[1].x * inv9;
            local += cr * cr / (iv * jv + 1e-5f);
        }
        {
            const float cr = S5[4].y - S5[1].y * S5[0].y * inv9;
            const float iv = S5[2].y - S5[0].y * S5[0].y * inv9;
            const float jv = S5[3].y - S5[1].y * S5[1].y * inv9;
            local += cr * cr / (iv * jv + 1e-5f);
        }
        {
            const float cr = S5[4].z - S5[1].z * S5[0].z * inv9;
            const float iv = S5[2].z - S5[0].z * S5[0].z * inv9;
            const float jv = S5[3].z - S5[1].z * S5[1].z * inv9;
            local += cr * cr / (iv * jv + 1e-5f);
        }
        {
            const float cr = S5[4].w - S5[1].w * S5[0].w * inv9;
            const float iv = S5[2].w - S5[0].w * S5[0].w * inv9;
            const float jv = S5[3].w - S5[1].w * S5[1].w * inv9;
            local += cr * cr / (iv * jv + 1e-5f);
        }
        __syncthreads();                     // WAR: next step overwrites sbuf
    }

    red[tid] = local;
    if (tid < 192) red[320 + tid] = 0.f;
    __syncthreads();
    for (int off = 256; off > 0; off >>= 1) {
        if (tid < off) red[tid] += red[tid + off];
        __syncthreads();
    }
    if (tid == 0) atomicAdd(acc, (double)red[0]);
}

__global__ void k_final(const double* __restrict__ acc, float* __restrict__ out) {
    out[0] = (float)(-(*acc) / (double)NV_);
}

extern "C" void kernel_launch(void* const* d_in, const int* in_sizes, int n_in,
                              void* d_out, int out_size, void* d_ws, size_t ws_size,
                              hipStream_t stream) {
    const float* I = (const float*)d_in[0];  // y_true
    const float* J = (const float*)d_in[1];  // y_pred
    float* out = (float*)d_out;

    if (ws_size < sizeof(double)) return;    // needs only 8 bytes of scratch
    double* acc = (double*)d_ws;

    k_zero<<<1, 1, 0, stream>>>(acc);
    kf_fused<<<NZC * (B_ * H_ / ROWS), ROWS * W4_, 0, stream>>>(I, J, acc);
    k_final<<<1, 1, 0, stream>>>(acc, out);
}